// Round 14
// baseline (21.015 us; speedup 1.0000x reference)
//
#include <hip/hip_runtime.h>

typedef unsigned long long u64;
typedef unsigned int u32;

#define W    4096
#define NT   128
#define CH   32          // one thread per 32-wide chunk (= dist)
#define NCH  128
#define D32  32

__global__ __launch_bounds__(NT) void extrema_nms_r14(
    const float* __restrict__ x,
    const int*   __restrict__ dist_p,
    float*       __restrict__ out)
{
    const int sig = blockIdx.x;
    const float* xg = x + (size_t)sig * W;
    float*       og = out + (size_t)sig * W;
    const int dist = *dist_p;
    const int tid  = threadIdx.x;

    __shared__ u64 HM[NCH + 2];   // chunk candidates (key<<32 | globalpos), padded
    __shared__ u32 KF[NCH + 2];   // round-stamped kill flags, padded
    __shared__ int LF;            // round-stamped live flag
    __shared__ u64 SK[W];         // fallback only (32 KB)

    if (dist == D32) {
        const int base = tid * CH;

        // ---- input straight to registers; 2 scalar boundary loads ----
        float f[CH + 2];
        {
            const float4* xg4 = (const float4*)xg + tid * 8;
            #pragma unroll
            for (int v = 0; v < 8; ++v) {
                const float4 q = xg4[v];
                f[4*v+1] = q.x; f[4*v+2] = q.y; f[4*v+3] = q.z; f[4*v+4] = q.w;
            }
            f[0]      = (tid > 0)      ? xg[base - 1]  : __int_as_float(0x7f800000); // left=true at i=0
            f[CH + 1] = (tid < NT - 1) ? xg[base + CH] : f[CH];                       // right=false at i=W-1
        }
        // ---- extrema keys: u32 (ab<<1)|1, 0 = not extremum. Ties by position
        // handled structurally (leftmost in-chunk; strict > vs left chunk,
        // >= vs right chunk) == stable-argsort order (proven R7/R13).
        u32 kb[CH];
        #pragma unroll
        for (int j = 0; j < CH; ++j) {
            const float xi = f[j + 1];
            const bool right = f[j + 2] > xi;
            const bool left  = xi <= f[j];
            const bool s     = xi <= 0.0f;
            const bool ext   = (right && left && s) || (!right && !left && !s);
            kb[j] = ext ? (((__float_as_uint(xi) & 0x7fffffffu) << 1) | 1u) : 0u;
        }
        u32 P = 0;                          // live mask
        #pragma unroll
        for (int j = 0; j < CH; ++j) if (kb[j]) P |= 1u << j;
        u32 best = 0; int bo = 0;           // leftmost argmax over live
        #pragma unroll
        for (int j = 0; j < CH; ++j) if (kb[j] > best) { best = kb[j]; bo = j; }

        if (tid < 2) { HM[tid * (NCH + 1)] = 0ull; KF[tid * (NCH + 1)] = 0u; } // pads
        KF[tid + 1] = 0u;
        if (tid == 0) LF = 0;
        // (init writes ordered before any cross-thread read by round-1's B1)

        int kpos = -1;
        for (int r = 1;; ++r) {
            HM[tid + 1] = best ? (((u64)best << 32) | (u32)(base + bo)) : 0ull;
            const u64 bal = __ballot(best != 0u);
            if ((tid & 63) == 0 && bal) LF = r;
            __syncthreads();                            // B1
            const int lf = LF;
            const u64 hL = HM[tid];                     // chunk c-1 candidate
            const u64 hR = HM[tid + 2];                 // chunk c+1 candidate
            if (lf != r) break;                         // uniform: nothing live

            const u32 ML = (u32)(hL >> 32); const int jm = (int)(u32)hL;
            const u32 MR = (u32)(hR >> 32); const int jp = (int)(u32)hR;

            // push-kill: do my live elements suppress neighbor candidates?
            if (ML && best > ML) {                      // left: strict > (left wins ties)
                const int e = jm + D32 - base;          // elements j <= e are within 32
                u32 kill = 0;
                #pragma unroll
                for (int j = 0; j < CH; ++j)
                    kill |= (j <= e && ((P >> j) & 1u) && kb[j] > ML) ? 1u : 0u;
                if (kill) KF[tid] = (u32)r;             // stamp chunk c-1
            }
            if (MR && best >= MR) {                     // right: >= (I win ties)
                const int s2 = jp - D32 - base;         // elements j >= s2 are within 32
                u32 kill = 0;
                #pragma unroll
                for (int j = 0; j < CH; ++j)
                    kill |= (j >= s2 && ((P >> j) & 1u) && kb[j] >= MR) ? 1u : 0u;
                if (kill) KF[tid + 2] = (u32)r;         // stamp chunk c+1
            }
            __syncthreads();                            // B2
            const u32 kfL = KF[tid];
            const u32 kfC = KF[tid + 1];
            const u32 kfR = KF[tid + 2];
            const bool keep_m = ML && (kfL != (u32)r);
            const bool keep_c = best && (kfC != (u32)r);
            const bool keep_p = MR && (kfR != (u32)r);

            // kills as contiguous bit-range masks
            u32 newP = P;
            if (keep_m) { const int e  = jm + D32 - base;   // [0,31]
                          newP &= (e >= 31) ? 0u : ~((1u << (e + 1)) - 1u); }
            if (keep_p) { const int s2 = jp - D32 - base;   // [0,31]
                          newP &= (s2 <= 0) ? 0u : ~(0xffffffffu << s2); }
            if (keep_c) { kpos = bo; newP = 0u; }           // keeper covers whole chunk
            if (newP != P) {
                P = newP;
                if (!((P >> bo) & 1u)) {                    // candidate died -> rescan
                    best = 0;
                    #pragma unroll
                    for (int j = 0; j < CH; ++j) {
                        const u32 kj = ((P >> j) & 1u) ? kb[j] : 0u;
                        best = kj > best ? kj : best;
                    }
                    bo = 0;
                    if (best) {
                        #pragma unroll
                        for (int j = CH - 1; j >= 0; --j) {  // last match = leftmost
                            const u32 kj = ((P >> j) & 1u) ? kb[j] : 0u;
                            if (kj == best) bo = j;
                        }
                    }
                }
            }
        }

        // ---- output straight from registers ----
        {
            float4* og4 = (float4*)og + tid * 8;
            #pragma unroll
            for (int v = 0; v < 8; ++v) {
                const int j0 = 4 * v;
                float4 o;
                o.x = (kpos == j0    ) ? f[j0 + 1] : 0.0f;
                o.y = (kpos == j0 + 1) ? f[j0 + 2] : 0.0f;
                o.z = (kpos == j0 + 2) ? f[j0 + 3] : 0.0f;
                o.w = (kpos == j0 + 3) ? f[j0 + 4] : 0.0f;
                og4[v] = o;
            }
        }
    } else {
        // ---------- generic fallback (any dist): proven serial greedy ----------
        for (int i = tid; i < W; i += NT) og[i] = 0.0f;
        for (int i = tid; i < W; i += NT) {
            const float xi = xg[i];
            const bool right = (i < W - 1) ? (xg[i + 1] > xi) : false;
            const bool left  = (i > 0)     ? (xi <= xg[i - 1]) : true;
            const bool s = (xi <= 0.0f);
            const bool valley = right && left && s;
            const bool peak   = !right && !left && !s;
            const u32 ab = __float_as_uint(xi) & 0x7fffffffu;
            SK[i] = (valley || peak) ? (((u64)ab << 32) | (u64)(u32)(W - 1 - i)) : 0ull;
        }
        __syncthreads();

        for (;;) {
            u64 m = 0ull;
            #pragma unroll
            for (int j = 0; j < W / NT; ++j) {
                const u64 k = SK[tid + j * NT];
                if (k > m) m = k;
            }
            #pragma unroll
            for (int off = 32; off > 0; off >>= 1) {
                const u64 o = __shfl_down(m, off, 64);
                if (o > m) m = o;
            }
            if ((tid & 63) == 0) HM[tid >> 6] = m;
            __syncthreads();
            if (tid == 0 && HM[1] > HM[0]) HM[0] = HM[1];
            __syncthreads();
            const u64 win = HM[0];
            if (win == 0ull) break;

            const int p = (W - 1) - (int)(win & 0xffffffffu);
            if (tid == 0) og[p] = xg[p];

            int lo = p - dist; lo = lo < 0 ? 0 : lo;
            int hi = p + dist; hi = hi > (W - 1) ? (W - 1) : hi;
            for (int j = lo + tid; j <= hi; j += NT) SK[j] = 0ull;
            __syncthreads();
        }
    }
}

extern "C" void kernel_launch(void* const* d_in, const int* in_sizes, int n_in,
                              void* d_out, int out_size, void* d_ws, size_t ws_size,
                              hipStream_t stream) {
    const float* x      = (const float*)d_in[0];
    const int*   dist_p = (const int*)d_in[1];
    float*       out    = (float*)d_out;
    const int nsig = in_sizes[0] / W;   // 128 signals of length 4096
    hipLaunchKernelGGL(extrema_nms_r14, dim3(nsig), dim3(NT), 0, stream,
                       x, dist_p, out);
}